// Round 1
// baseline (1179.416 us; speedup 1.0000x reference)
//
#include <hip/hip_runtime.h>
#include <math.h>

#define BN_EPS 1e-5f

__device__ __forceinline__ float hswish(float z){
    float c = fminf(fmaxf(z + 3.0f, 0.0f), 6.0f);
    return z * c * (1.0f/6.0f);
}

// ---------------- prep: A_norm (transposed, padded rows of 32) ----------------
// Atv[k][v][w] at Atv[(k*25+v)*32 + w],  w in 0..24 valid.
__global__ void prep_A(const float* __restrict__ Af, const float* __restrict__ Al,
                       float* __restrict__ Atv){
    int k = blockIdx.x;            // 0..2
    __shared__ float Ac[25][25];
    __shared__ float dpow[25];
    int tid = threadIdx.x;
    for (int i = tid; i < 625; i += blockDim.x){
        float a = Af[k*625 + i] + Al[k*625 + i];
        Ac[i/25][i%25] = fabsf(a);
    }
    __syncthreads();
    if (tid < 25){
        float s = 0.f;
        #pragma unroll
        for (int w = 0; w < 25; ++w) s += Ac[tid][w];
        s = fmaxf(s, 1e-6f);
        dpow[tid] = 1.0f / sqrtf(s);
    }
    __syncthreads();
    for (int i = tid; i < 625; i += blockDim.x){
        int v = i/25, w = i%25;
        Atv[(k*25 + v)*32 + w] = dpow[v] * Ac[v][w] * dpow[w];
    }
}

// ---------------- prep: W transpose + fold BN scale and 1/K ----------------
// Wt[k][c][o] = W[k][o][c] * gamma[o]/sqrt(1+eps) / 3
__global__ void prep_W(const float* __restrict__ W, const float* __restrict__ gamma,
                       float* __restrict__ Wt){
    int c = blockIdx.x;            // 0..127
    int k = blockIdx.y;            // 0..2
    int o = threadIdx.x;           // 0..127
    float scale = gamma[o] * (1.0f / sqrtf(1.0f + BN_EPS)) * (1.0f/3.0f);
    Wt[(k*128 + c)*128 + o] = W[(k*128 + o)*128 + c] * scale;
}

// ---------------- main fused kernel ----------------
// grid (50 m-tiles, 64 b), 512 threads (8 waves). m = t*25+w linear over 6400.
// Per k: XA[c][m_local] built in LDS (x from global, A from SGPRs),
// then GEMM: wave w owns 16 o's (W row via s_load_dwordx16), lanes own m.
__global__ __launch_bounds__(512, 4) void gcn_main(
    const float* __restrict__ x, const float* __restrict__ Atv,
    const float* __restrict__ Wt, const float* __restrict__ beta,
    float* __restrict__ out){
    extern __shared__ float XA[];          // [128][132] floats = 67584 B
    const int tile = blockIdx.x;           // 0..49
    const int b    = blockIdx.y;           // 0..63
    const int tid  = threadIdx.x;
    const int lane = tid & 63;
    const int wv   = __builtin_amdgcn_readfirstlane(tid >> 6);   // 0..7 wave-uniform
    const int o0   = wv * 16;

    const int m0  = tile * 128;
    const int t0  = m0 / 25;
    const int off = m0 - t0 * 25;          // 0..24

    float acc[16][2];
    #pragma unroll
    for (int j = 0; j < 16; ++j){ acc[j][0] = 0.f; acc[j][1] = 0.f; }

    for (int k = 0; k < 3; ++k){
        // ---- XA phase: tasks (c, tloc) 128*7=896; A rows from scalar cache ----
        for (int task = tid; task < 896; task += 512){
            int c    = task / 7;
            int tloc = task % 7;
            int t    = t0 + tloc;
            if (t < 256){
                const float* xrow = x + (((b*128 + c)*256 + t)*25);
                float pacc[25];
                #pragma unroll
                for (int w = 0; w < 25; ++w) pacc[w] = 0.f;
                #pragma unroll 2
                for (int v = 0; v < 25; ++v){
                    float xv = xrow[v];
                    const float* at = Atv + (k*25 + v)*32;   // uniform -> s_load
                    #pragma unroll
                    for (int w = 0; w < 25; ++w)
                        pacc[w] = fmaf(xv, at[w], pacc[w]);
                }
                int base = tloc*25 - off;
                #pragma unroll
                for (int w = 0; w < 25; ++w){
                    int lm = base + w;
                    if (lm >= 0 && lm < 128) XA[c*132 + lm] = pacc[w];
                }
            }
        }
        __syncthreads();
        // ---- GEMM phase: y[m, o0..o0+15] += sum_c XA[c][m] * Wt[k][c][o] ----
        const float* wbase = Wt + (k*128)*128 + o0;
        #pragma unroll 2
        for (int c = 0; c < 128; ++c){
            float xa0 = XA[c*132 + lane];
            float xa1 = XA[c*132 + lane + 64];
            const float* wr = wbase + c*128;                 // uniform -> s_load x16
            #pragma unroll
            for (int j = 0; j < 16; ++j){
                float wj = wr[j];
                acc[j][0] = fmaf(wj, xa0, acc[j][0]);
                acc[j][1] = fmaf(wj, xa1, acc[j][1]);
            }
        }
        __syncthreads();
    }

    // ---- epilogue: + beta, hardswish, + residual x, hardswish, store ----
    #pragma unroll
    for (int j = 0; j < 16; ++j){
        int o = o0 + j;
        float bet = beta[o];                                  // uniform -> s_load
        #pragma unroll
        for (int h = 0; h < 2; ++h){
            int m    = lane + h*64;
            int xoff = (b*128 + o)*6400 + m0 + m;
            float val = acc[j][h] + bet;      // BN scale & 1/K folded into Wt
            float h1  = hswish(val);
            out[xoff] = hswish(h1 + x[xoff]);
        }
    }
}

extern "C" void kernel_launch(void* const* d_in, const int* in_sizes, int n_in,
                              void* d_out, int out_size, void* d_ws, size_t ws_size,
                              hipStream_t stream) {
    const float* x      = (const float*)d_in[0];
    const float* Afix   = (const float*)d_in[1];
    const float* Alrn   = (const float*)d_in[2];
    const float* Wg     = (const float*)d_in[3];
    const float* gamma  = (const float*)d_in[4];
    const float* beta   = (const float*)d_in[5];
    float* out = (float*)d_out;

    float* Wt  = (float*)d_ws;                 // 3*128*128 floats
    float* Atv = Wt + 3*128*128;               // 3*25*32 floats

    (void)hipFuncSetAttribute((const void*)gcn_main,
                              hipFuncAttributeMaxDynamicSharedMemorySize, 67584);

    prep_A<<<dim3(3), 256, 0, stream>>>(Afix, Alrn, Atv);
    prep_W<<<dim3(128, 3), 128, 0, stream>>>(Wg, gamma, Wt);
    gcn_main<<<dim3(50, 64), 512, 67584, stream>>>(x, Atv, Wt, beta, out);
}

// Round 3
// 680.098 us; speedup vs baseline: 1.7342x; 1.7342x over previous
//
#include <hip/hip_runtime.h>
#include <math.h>

#define BN_EPS 1e-5f

typedef __attribute__((ext_vector_type(4))) float f32x4;
typedef __attribute__((ext_vector_type(8))) __bf16 bf16x8;
typedef __attribute__((ext_vector_type(4))) unsigned int u32x4;

static __device__ __forceinline__ float hswish(float z){
    float c = fminf(fmaxf(z + 3.0f, 0.0f), 6.0f);
    return z * c * (1.0f/6.0f);
}
// RNE float->bf16 bits
static __device__ __forceinline__ unsigned short bf16bits(float f){
    unsigned int u = __builtin_bit_cast(unsigned int, f);
    unsigned int r = u + 0x7FFFu + ((u >> 16) & 1u);
    return (unsigned short)(r >> 16);
}
static __device__ __forceinline__ float bf16f(unsigned short h){
    return __builtin_bit_cast(float, ((unsigned int)h) << 16);
}

// ---------------- prep: A_norm fp32, padded rows of 32 ----------------
// Atv[(k*25+v)*32 + w], w in 0..24 valid.
__global__ void prep_A(const float* __restrict__ Af, const float* __restrict__ Al,
                       float* __restrict__ Atv){
    int k = blockIdx.x;
    __shared__ float Ac[25][25];
    __shared__ float dpow[25];
    int tid = threadIdx.x;
    for (int i = tid; i < 625; i += blockDim.x){
        float a = Af[k*625 + i] + Al[k*625 + i];
        Ac[i/25][i%25] = fabsf(a);
    }
    __syncthreads();
    if (tid < 25){
        float s = 0.f;
        #pragma unroll
        for (int w = 0; w < 25; ++w) s += Ac[tid][w];
        s = fmaxf(s, 1e-6f);
        dpow[tid] = 1.0f / sqrtf(s);
    }
    __syncthreads();
    for (int i = tid; i < 625; i += blockDim.x){
        int v = i/25, w = i%25;
        Atv[(k*25 + v)*32 + w] = dpow[v] * Ac[v][w] * dpow[w];
    }
}

// ---------------- prep: W -> bf16 B-fragment layout ----------------
// frag fidx = (ks*8 + ot), ks = k*4 + c0 (kc-chunk of 32), ot = o-tile of 16.
// lane l supplies 8 bf16: B[slot = c0*32 + (l>>4)*8 + i][o = ot*16 + (l&15)]
// value = W[k][o][c] * gamma[o]/sqrt(1+eps)/3   (BN scale and 1/K folded)
__global__ void prep_W(const float* __restrict__ W, const float* __restrict__ gamma,
                       unsigned int* __restrict__ Wf){
    int fidx = blockIdx.x;              // 0..95
    int ot = fidx & 7, c0 = (fidx >> 3) & 3, k = fidx >> 5;
    int l = threadIdx.x;                // 0..63
    int o = ot*16 + (l & 15);
    int cb = c0*32 + ((l >> 4) << 3);
    float scale = gamma[o] * rsqrtf(1.0f + BN_EPS) * (1.0f/3.0f);
    const float* wr = W + (k*128 + o)*128 + cb;
    unsigned int p0, p1, p2, p3;
    p0 = (unsigned int)bf16bits(wr[0]*scale) | ((unsigned int)bf16bits(wr[1]*scale) << 16);
    p1 = (unsigned int)bf16bits(wr[2]*scale) | ((unsigned int)bf16bits(wr[3]*scale) << 16);
    p2 = (unsigned int)bf16bits(wr[4]*scale) | ((unsigned int)bf16bits(wr[5]*scale) << 16);
    p3 = (unsigned int)bf16bits(wr[6]*scale) | ((unsigned int)bf16bits(wr[7]*scale) << 16);
    u32x4 v = {p0, p1, p2, p3};
    ((u32x4*)Wf)[fidx*64 + l] = v;
}

// ---------------- main fused kernel ----------------
// grid (128 tiles of 50 m, 64 b), 512 threads (8 waves).
// LDS: XA bf16 [64 m][384 kc] swizzled (49152 B) | xslab bf16 [128 c][54] (13824 B)
//      outstage fp32 [128 o][65 m] overlays XA after GEMM (33280 B < 49152 B).
__global__ __launch_bounds__(512, 4) void gcn_main(
    const float* __restrict__ x, const float* __restrict__ Atv,
    const unsigned int* __restrict__ Wf, const float* __restrict__ beta,
    float* __restrict__ out){
    extern __shared__ char smem[];
    unsigned short* lds16 = (unsigned short*)smem;
    const int XS = 24576;                  // halfword base of xslab (=49152 B)
    const int tile = blockIdx.x;           // 0..127
    const int b    = blockIdx.y;           // 0..63
    const int tid  = threadIdx.x;
    const int lane = tid & 63;
    const int wv   = tid >> 6;
    const int m0g  = tile * 50;
    const int t0   = tile * 2;             // 50 = 2*25, t-aligned

    // ---- Phase 1: stage x slab (fp32 -> bf16), coalesced ----
    {
        int xbase = (b*128)*6400 + t0*25;  // element offset for c=0
        for (int j = tid; j < 6400; j += 512){
            int c = j / 50, tv = j - c*50;
            float f = x[xbase + c*6400 + tv];
            lds16[XS + c*54 + tv] = bf16bits(f);
        }
    }
    __syncthreads();

    // ---- Phase 2: XA = x . A_norm (fp32 VALU), write bf16 swizzled ----
    for (int task = wv; task < 12; task += 8){
        int kk   = __builtin_amdgcn_readfirstlane(task >> 2);        // 0..2
        int tloc = __builtin_amdgcn_readfirstlane((task >> 1) & 1);  // 0..1
        int ch   = task & 1;
        int c = ch*64 + lane;
        float pacc[25];
        #pragma unroll
        for (int w = 0; w < 25; ++w) pacc[w] = 0.f;
        const float* Ak = Atv + kk*800;
        #pragma unroll 5
        for (int v = 0; v < 25; ++v){
            float xv = bf16f(lds16[XS + c*54 + tloc*25 + v]);
            const float* Ar = Ak + v*32;        // wave-uniform -> s_load
            #pragma unroll
            for (int w = 0; w < 25; ++w)
                pacc[w] = fmaf(xv, Ar[w], pacc[w]);
        }
        #pragma unroll
        for (int w = 0; w < 25; ++w){
            int m = tloc*25 + w;                 // 0..49
            int hw = m*384 + kk*128 + c;
            int byteoff = (hw << 1) ^ ((m & 7) << 4);
            *(unsigned short*)(smem + byteoff) = bf16bits(pacc[w]);
        }
    }
    __syncthreads();

    // ---- Phase 3: GEMM via MFMA 16x16x32 bf16 over kc=384 ----
    const int mh = wv >> 2;                 // 0..1 : m-half (32 rows)
    const int oq = wv & 3;                  // 0..3 : o-quarter (32 cols)
    const int r = lane & 15, g = lane >> 4;
    const int swz = (r & 7) << 4;
    f32x4 acc00 = {0.f,0.f,0.f,0.f}, acc01 = {0.f,0.f,0.f,0.f};
    f32x4 acc10 = {0.f,0.f,0.f,0.f}, acc11 = {0.f,0.f,0.f,0.f};
    const int abU0 = (mh*32 + r) * 768 + g*16;   // unswizzled byte base (+ks*64)
    const int abU1 = abU0 + 16*768;
    const u32x4* WfV = (const u32x4*)Wf;
    const int ot0 = oq*2, ot1 = ot0 + 1;
    u32x4 b0 = WfV[(ot0)*64 + lane];
    u32x4 b1 = WfV[(ot1)*64 + lane];
    #pragma unroll
    for (int ks = 0; ks < 12; ++ks){
        u32x4 nb0 = b0, nb1 = b1;
        if (ks < 11){
            nb0 = WfV[((ks+1)*8 + ot0)*64 + lane];
            nb1 = WfV[((ks+1)*8 + ot1)*64 + lane];
        }
        bf16x8 a0 = *(const bf16x8*)(smem + ((abU0 + ks*64) ^ swz));
        bf16x8 a1 = *(const bf16x8*)(smem + ((abU1 + ks*64) ^ swz));
        bf16x8 f0 = __builtin_bit_cast(bf16x8, b0);
        bf16x8 f1 = __builtin_bit_cast(bf16x8, b1);
        acc00 = __builtin_amdgcn_mfma_f32_16x16x32_bf16(a0, f0, acc00, 0, 0, 0);
        acc01 = __builtin_amdgcn_mfma_f32_16x16x32_bf16(a0, f1, acc01, 0, 0, 0);
        acc10 = __builtin_amdgcn_mfma_f32_16x16x32_bf16(a1, f0, acc10, 0, 0, 0);
        acc11 = __builtin_amdgcn_mfma_f32_16x16x32_bf16(a1, f1, acc11, 0, 0, 0);
        b0 = nb0; b1 = nb1;
    }
    __syncthreads();

    // ---- Phase 4: acc -> outstage fp32 [o][65] (overlays XA region) ----
    // D[m = g*4+e (+16 for a1 rows)][o = r (+16 for f1 cols)] per m89 C/D map.
    // Stride 65: max index o*65+63 < 128*65, so garbage rows m=50..63 land in
    // padding, never aliasing valid entries (stride-57 version had a WW race).
    {
        float* outst = (float*)smem;
        #pragma unroll
        for (int e = 0; e < 4; ++e){
            int o0 = oq*32 + r, o1 = o0 + 16;
            int mA = mh*32 + g*4 + e, mB = mA + 16;
            outst[o0*65 + mA] = acc00[e];
            outst[o1*65 + mA] = acc01[e];
            outst[o0*65 + mB] = acc10[e];
            outst[o1*65 + mB] = acc11[e];
        }
    }
    __syncthreads();

    // ---- Phase 5: readout + epilogue (+beta, hswish, +x, hswish) ----
    {
        const float* outst = (const float*)smem;
        int o = tid >> 2, q = tid & 3;
        float bet = beta[o];
        int obase = (b*128 + o)*6400 + m0g;
        int nj = (q < 3) ? 8 : 1;              // q=3 covers only m=48,49
        for (int j2 = 0; j2 < nj; ++j2){
            int m = q*16 + 2*j2;
            float v0 = outst[o*65 + m];
            float v1 = outst[o*65 + m + 1];
            float2 xr = *(const float2*)(x + obase + m);
            float r0 = hswish(hswish(v0 + bet) + xr.x);
            float r1 = hswish(hswish(v1 + bet) + xr.y);
            float2 res = {r0, r1};
            *(float2*)(out + obase + m) = res;
        }
    }
}

extern "C" void kernel_launch(void* const* d_in, const int* in_sizes, int n_in,
                              void* d_out, int out_size, void* d_ws, size_t ws_size,
                              hipStream_t stream) {
    const float* x      = (const float*)d_in[0];
    const float* Afix   = (const float*)d_in[1];
    const float* Alrn   = (const float*)d_in[2];
    const float* Wg     = (const float*)d_in[3];
    const float* gamma  = (const float*)d_in[4];
    const float* beta   = (const float*)d_in[5];
    float* out = (float*)d_out;

    float* Atv = (float*)d_ws;                                   // 9600 B
    unsigned int* Wf = (unsigned int*)((char*)d_ws + 16384);     // 98304 B

    (void)hipFuncSetAttribute((const void*)gcn_main,
                              hipFuncAttributeMaxDynamicSharedMemorySize, 62976);

    prep_A<<<dim3(3), 256, 0, stream>>>(Afix, Alrn, Atv);
    prep_W<<<dim3(96), 64, 0, stream>>>(Wg, gamma, Wf);
    gcn_main<<<dim3(128, 64), 512, 62976, stream>>>(x, Atv, Wf, beta, out);
}

// Round 4
// 584.420 us; speedup vs baseline: 2.0181x; 1.1637x over previous
//
#include <hip/hip_runtime.h>
#include <math.h>

#define BN_EPS 1e-5f

typedef __attribute__((ext_vector_type(4)))  float f32x4;
typedef __attribute__((ext_vector_type(16))) float f32x16;
typedef __attribute__((ext_vector_type(8)))  __bf16 bf16x8;
typedef __attribute__((ext_vector_type(8)))  unsigned short u16x8;
typedef __attribute__((ext_vector_type(4)))  unsigned int u32x4;

static __device__ __forceinline__ float hswish(float z){
    float c = fminf(fmaxf(z + 3.0f, 0.0f), 6.0f);
    return z * c * (1.0f/6.0f);
}
// RNE float->bf16 bits
static __device__ __forceinline__ unsigned short bf16bits(float f){
    unsigned int u = __builtin_bit_cast(unsigned int, f);
    unsigned int r = u + 0x7FFFu + ((u >> 16) & 1u);
    return (unsigned short)(r >> 16);
}
static __device__ __forceinline__ float bf16f(unsigned short h){
    return __builtin_bit_cast(float, ((unsigned int)h) << 16);
}

// ---------------- prep: A_norm fp32, padded rows of 32 ----------------
__global__ void prep_A(const float* __restrict__ Af, const float* __restrict__ Al,
                       float* __restrict__ Atv){
    int k = blockIdx.x;
    __shared__ float Ac[25][25];
    __shared__ float dpow[25];
    int tid = threadIdx.x;
    for (int i = tid; i < 625; i += blockDim.x){
        float a = Af[k*625 + i] + Al[k*625 + i];
        Ac[i/25][i%25] = fabsf(a);
    }
    __syncthreads();
    if (tid < 25){
        float s = 0.f;
        #pragma unroll
        for (int w = 0; w < 25; ++w) s += Ac[tid][w];
        s = fmaxf(s, 1e-6f);
        dpow[tid] = 1.0f / sqrtf(s);
    }
    __syncthreads();
    for (int i = tid; i < 625; i += blockDim.x){
        int v = i/25, w = i%25;
        Atv[(k*25 + v)*32 + w] = dpow[v] * Ac[v][w] * dpow[w];
    }
}

// ---------------- prep: A_norm -> 32x32x16 B-fragments, hi/lo bf16 split ----
// frag index f = (k*2 + half)*2 + hl; per lane 8 bf16 = u32x4.
// B[slot s = (lane>>5)*8 + i][col w = lane&31], v = half*16 + s.
__global__ void prep_Afrag(const float* __restrict__ Atv, u32x4* __restrict__ Af2){
    int blk  = blockIdx.x;            // 0..5 = k*2 + half
    int k    = blk >> 1, half = blk & 1;
    int l    = threadIdx.x;           // 0..63
    int w    = l & 31, g = l >> 5;
    unsigned short hi[8], lo[8];
    #pragma unroll
    for (int i = 0; i < 8; ++i){
        int v = half*16 + g*8 + i;
        float val = (v < 25 && w < 25) ? Atv[(k*25 + v)*32 + w] : 0.f;
        unsigned short h = bf16bits(val);
        hi[i] = h;
        lo[i] = bf16bits(val - bf16f(h));
    }
    u32x4 H = { (unsigned)hi[0] | ((unsigned)hi[1]<<16), (unsigned)hi[2] | ((unsigned)hi[3]<<16),
                (unsigned)hi[4] | ((unsigned)hi[5]<<16), (unsigned)hi[6] | ((unsigned)hi[7]<<16) };
    u32x4 L = { (unsigned)lo[0] | ((unsigned)lo[1]<<16), (unsigned)lo[2] | ((unsigned)lo[3]<<16),
                (unsigned)lo[4] | ((unsigned)lo[5]<<16), (unsigned)lo[6] | ((unsigned)lo[7]<<16) };
    Af2[(blk*2 + 0)*64 + l] = H;
    Af2[(blk*2 + 1)*64 + l] = L;
}

// ---------------- prep: W -> bf16 B-fragment layout (16x16x32) ----------------
__global__ void prep_W(const float* __restrict__ W, const float* __restrict__ gamma,
                       unsigned int* __restrict__ Wf){
    int fidx = blockIdx.x;              // 0..95
    int ot = fidx & 7, c0 = (fidx >> 3) & 3, k = fidx >> 5;
    int l = threadIdx.x;                // 0..63
    int o = ot*16 + (l & 15);
    int cb = c0*32 + ((l >> 4) << 3);
    float scale = gamma[o] * rsqrtf(1.0f + BN_EPS) * (1.0f/3.0f);
    const float* wr = W + (k*128 + o)*128 + cb;
    unsigned int p0, p1, p2, p3;
    p0 = (unsigned int)bf16bits(wr[0]*scale) | ((unsigned int)bf16bits(wr[1]*scale) << 16);
    p1 = (unsigned int)bf16bits(wr[2]*scale) | ((unsigned int)bf16bits(wr[3]*scale) << 16);
    p2 = (unsigned int)bf16bits(wr[4]*scale) | ((unsigned int)bf16bits(wr[5]*scale) << 16);
    p3 = (unsigned int)bf16bits(wr[6]*scale) | ((unsigned int)bf16bits(wr[7]*scale) << 16);
    u32x4 v = {p0, p1, p2, p3};
    ((u32x4*)Wf)[fidx*64 + l] = v;
}

// ---------------- main fused kernel ----------------
// grid (128 tiles of 50 m, 64 b), 512 threads (8 waves). LDS 49152 B:
//   P1: XA bf16 [64 m][384 kc] swizzled, built via mfma_32x32x16 from global x
//   P2: GEMM 16x16x32 over kc=384
//   P3: outstage fp32 [128 o][65 m] overlays XA (33280 B)
//   P4: epilogue
__global__ __launch_bounds__(512, 4) void gcn_main(
    const float* __restrict__ x, const u32x4* __restrict__ Af2,
    const unsigned int* __restrict__ Wf, const float* __restrict__ beta,
    float* __restrict__ out){
    extern __shared__ char smem[];
    const int tile = blockIdx.x;           // 0..127
    const int b    = blockIdx.y;           // 0..63
    const int tid  = threadIdx.x;
    const int lane = tid & 63;
    const int wv   = tid >> 6;
    const int m0g  = tile * 50;
    const int t0   = tile * 2;             // 50 = 2*25, t-aligned

    // ================= P1: XA via MFMA 32x32x16 =================
    // wave task: (c32 = wv&3, tt = wv>>2). lane&31 = c-row for A, = w-col for D.
    {
        const int c32 = wv & 3, tt = wv >> 2;
        const int lw  = lane & 31, g5 = lane >> 5;
        const int c   = c32*32 + lw;
        const float* xrow = x + (((size_t)(b*128 + c)*256 + (t0 + tt))*25);

        float a0f[8], a1f[8];
        #pragma unroll
        for (int i = 0; i < 8; ++i) a0f[i] = xrow[g5*8 + i];      // v = g5*8+i (<16)
        if (g5 == 0){
            #pragma unroll
            for (int i = 0; i < 8; ++i) a1f[i] = xrow[16 + i];    // v 16..23
        } else {
            a1f[0] = xrow[24];                                    // v 24; 25..31 pad
            #pragma unroll
            for (int i = 1; i < 8; ++i) a1f[i] = 0.f;
        }
        u16x8 ua0, ua1;
        #pragma unroll
        for (int i = 0; i < 8; ++i){ ua0[i] = bf16bits(a0f[i]); ua1[i] = bf16bits(a1f[i]); }
        bf16x8 A0 = __builtin_bit_cast(bf16x8, ua0);
        bf16x8 A1 = __builtin_bit_cast(bf16x8, ua1);

        const int mrow  = tt*25 + lw;            // XA row (w<25 valid)
        const int mbyte = mrow * 768;
        const int swzb  = (mrow & 7) << 4;

        for (int k = 0; k < 3; ++k){
            u32x4 B0h = Af2[((k*2+0)*2 + 0)*64 + lane];
            u32x4 B0l = Af2[((k*2+0)*2 + 1)*64 + lane];
            u32x4 B1h = Af2[((k*2+1)*2 + 0)*64 + lane];
            u32x4 B1l = Af2[((k*2+1)*2 + 1)*64 + lane];
            f32x16 acc;
            #pragma unroll
            for (int e = 0; e < 16; ++e) acc[e] = 0.f;
            acc = __builtin_amdgcn_mfma_f32_32x32x16_bf16(A1, __builtin_bit_cast(bf16x8, B1l), acc, 0,0,0);
            acc = __builtin_amdgcn_mfma_f32_32x32x16_bf16(A0, __builtin_bit_cast(bf16x8, B0l), acc, 0,0,0);
            acc = __builtin_amdgcn_mfma_f32_32x32x16_bf16(A1, __builtin_bit_cast(bf16x8, B1h), acc, 0,0,0);
            acc = __builtin_amdgcn_mfma_f32_32x32x16_bf16(A0, __builtin_bit_cast(bf16x8, B0h), acc, 0,0,0);
            if (lw < 25){
                #pragma unroll
                for (int q = 0; q < 4; ++q){
                    int rowD = 8*q + 4*g5;                         // D rows rowD..rowD+3
                    int kc   = k*128 + c32*32 + rowD;
                    unsigned int d0 = (unsigned int)bf16bits(acc[4*q+0]) | ((unsigned int)bf16bits(acc[4*q+1]) << 16);
                    unsigned int d1 = (unsigned int)bf16bits(acc[4*q+2]) | ((unsigned int)bf16bits(acc[4*q+3]) << 16);
                    int byteoff = (mbyte + kc*2) ^ swzb;
                    uint2 vv = {d0, d1};
                    *(uint2*)(smem + byteoff) = vv;
                }
            }
        }
    }
    __syncthreads();

    // ================= P2: GEMM via MFMA 16x16x32 over kc=384 =================
    const int mh = wv >> 2;                 // 0..1 : m-half (32 rows)
    const int oq = wv & 3;                  // 0..3 : o-quarter (32 cols)
    const int r = lane & 15, g = lane >> 4;
    const int swz = (r & 7) << 4;
    f32x4 acc00 = {0.f,0.f,0.f,0.f}, acc01 = {0.f,0.f,0.f,0.f};
    f32x4 acc10 = {0.f,0.f,0.f,0.f}, acc11 = {0.f,0.f,0.f,0.f};
    const int abU0 = (mh*32 + r) * 768 + g*16;   // unswizzled byte base (+ks*64)
    const int abU1 = abU0 + 16*768;
    const u32x4* WfV = (const u32x4*)Wf;
    const int ot0 = oq*2, ot1 = ot0 + 1;
    u32x4 b0 = WfV[(ot0)*64 + lane];
    u32x4 b1 = WfV[(ot1)*64 + lane];
    #pragma unroll
    for (int ks = 0; ks < 12; ++ks){
        u32x4 nb0 = b0, nb1 = b1;
        if (ks < 11){
            nb0 = WfV[((ks+1)*8 + ot0)*64 + lane];
            nb1 = WfV[((ks+1)*8 + ot1)*64 + lane];
        }
        bf16x8 a0 = *(const bf16x8*)(smem + ((abU0 + ks*64) ^ swz));
        bf16x8 a1 = *(const bf16x8*)(smem + ((abU1 + ks*64) ^ swz));
        bf16x8 f0 = __builtin_bit_cast(bf16x8, b0);
        bf16x8 f1 = __builtin_bit_cast(bf16x8, b1);
        acc00 = __builtin_amdgcn_mfma_f32_16x16x32_bf16(a0, f0, acc00, 0, 0, 0);
        acc01 = __builtin_amdgcn_mfma_f32_16x16x32_bf16(a0, f1, acc01, 0, 0, 0);
        acc10 = __builtin_amdgcn_mfma_f32_16x16x32_bf16(a1, f0, acc10, 0, 0, 0);
        acc11 = __builtin_amdgcn_mfma_f32_16x16x32_bf16(a1, f1, acc11, 0, 0, 0);
        b0 = nb0; b1 = nb1;
    }
    __syncthreads();

    // ================= P3: acc -> outstage fp32 [o][65] (overlays XA) =========
    // D[m = g*4+e (+16)][o = r (+16)]; garbage rows m=50..63 land in stride-65 pad.
    {
        float* outst = (float*)smem;
        #pragma unroll
        for (int e = 0; e < 4; ++e){
            int o0 = oq*32 + r, o1 = o0 + 16;
            int mA = mh*32 + g*4 + e, mB = mA + 16;
            outst[o0*65 + mA] = acc00[e];
            outst[o1*65 + mA] = acc01[e];
            outst[o0*65 + mB] = acc10[e];
            outst[o1*65 + mB] = acc11[e];
        }
    }
    __syncthreads();

    // ================= P4: epilogue (+beta, hswish, +x, hswish) ===============
    {
        const float* outst = (const float*)smem;
        int o = tid >> 2, q = tid & 3;
        float bet = beta[o];
        int obase = (b*128 + o)*6400 + m0g;
        int nj = (q < 3) ? 8 : 1;              // q=3 covers only m=48,49
        for (int j2 = 0; j2 < nj; ++j2){
            int m = q*16 + 2*j2;
            float v0 = outst[o*65 + m];
            float v1 = outst[o*65 + m + 1];
            float2 xr = *(const float2*)(x + obase + m);
            float r0 = hswish(hswish(v0 + bet) + xr.x);
            float r1 = hswish(hswish(v1 + bet) + xr.y);
            float2 res = {r0, r1};
            *(float2*)(out + obase + m) = res;
        }
    }
}

extern "C" void kernel_launch(void* const* d_in, const int* in_sizes, int n_in,
                              void* d_out, int out_size, void* d_ws, size_t ws_size,
                              hipStream_t stream) {
    const float* x      = (const float*)d_in[0];
    const float* Afix   = (const float*)d_in[1];
    const float* Alrn   = (const float*)d_in[2];
    const float* Wg     = (const float*)d_in[3];
    const float* gamma  = (const float*)d_in[4];
    const float* beta   = (const float*)d_in[5];
    float* out = (float*)d_out;

    float*        Atv = (float*)d_ws;                                // 9600 B
    unsigned int* Wf  = (unsigned int*)((char*)d_ws + 16384);        // 98304 B
    u32x4*        Af2 = (u32x4*)((char*)d_ws + 118784);              // 12288 B

    (void)hipFuncSetAttribute((const void*)gcn_main,
                              hipFuncAttributeMaxDynamicSharedMemorySize, 49152);

    prep_A<<<dim3(3), 256, 0, stream>>>(Afix, Alrn, Atv);
    prep_Afrag<<<dim3(6), 64, 0, stream>>>(Atv, Af2);
    prep_W<<<dim3(96), 64, 0, stream>>>(Wg, gamma, Wf);
    gcn_main<<<dim3(128, 64), 512, 49152, stream>>>(x, Af2, Wf, beta, out);
}

// Round 6
// 562.957 us; speedup vs baseline: 2.0950x; 1.0381x over previous
//
#include <hip/hip_runtime.h>
#include <math.h>

#define BN_EPS 1e-5f

typedef __attribute__((ext_vector_type(4)))  float f32x4;
typedef __attribute__((ext_vector_type(16))) float f32x16;
typedef __attribute__((ext_vector_type(8)))  __bf16 bf16x8;
typedef __attribute__((ext_vector_type(8)))  unsigned short u16x8;
typedef __attribute__((ext_vector_type(4)))  unsigned int u32x4;

static __device__ __forceinline__ float hswish(float z){
    float c = fminf(fmaxf(z + 3.0f, 0.0f), 6.0f);
    return z * c * (1.0f/6.0f);
}
// RNE float->bf16 bits
static __device__ __forceinline__ unsigned short bf16bits(float f){
    unsigned int u = __builtin_bit_cast(unsigned int, f);
    unsigned int r = u + 0x7FFFu + ((u >> 16) & 1u);
    return (unsigned short)(r >> 16);
}
static __device__ __forceinline__ float bf16f(unsigned short h){
    return __builtin_bit_cast(float, ((unsigned int)h) << 16);
}

// ---------------- prep: A_norm fp32, padded rows of 32 ----------------
__global__ void prep_A(const float* __restrict__ Af, const float* __restrict__ Al,
                       float* __restrict__ Atv){
    int k = blockIdx.x;
    __shared__ float Ac[25][25];
    __shared__ float dpow[25];
    int tid = threadIdx.x;
    for (int i = tid; i < 625; i += blockDim.x){
        float a = Af[k*625 + i] + Al[k*625 + i];
        Ac[i/25][i%25] = fabsf(a);
    }
    __syncthreads();
    if (tid < 25){
        float s = 0.f;
        #pragma unroll
        for (int w = 0; w < 25; ++w) s += Ac[tid][w];
        s = fmaxf(s, 1e-6f);
        dpow[tid] = 1.0f / sqrtf(s);
    }
    __syncthreads();
    for (int i = tid; i < 625; i += blockDim.x){
        int v = i/25, w = i%25;
        Atv[(k*25 + v)*32 + w] = dpow[v] * Ac[v][w] * dpow[w];
    }
}

// ---------------- prep: A_norm -> 32x32x16 B-fragments, hi/lo bf16 split ----
// frag index f = (k*2 + half)*2 + hl; per lane 8 bf16 = u32x4.
// B[slot s = (lane>>5)*8 + i][col w = lane&31], v = half*16 + s.
__global__ void prep_Afrag(const float* __restrict__ Atv, u32x4* __restrict__ Af2){
    int blk  = blockIdx.x;            // 0..5 = k*2 + half
    int k    = blk >> 1, half = blk & 1;
    int l    = threadIdx.x;           // 0..63
    int w    = l & 31, g = l >> 5;
    unsigned short hi[8], lo[8];
    #pragma unroll
    for (int i = 0; i < 8; ++i){
        int v = half*16 + g*8 + i;
        float val = (v < 25 && w < 25) ? Atv[(k*25 + v)*32 + w] : 0.f;
        unsigned short h = bf16bits(val);
        hi[i] = h;
        lo[i] = bf16bits(val - bf16f(h));
    }
    u32x4 H = { (unsigned)hi[0] | ((unsigned)hi[1]<<16), (unsigned)hi[2] | ((unsigned)hi[3]<<16),
                (unsigned)hi[4] | ((unsigned)hi[5]<<16), (unsigned)hi[6] | ((unsigned)hi[7]<<16) };
    u32x4 L = { (unsigned)lo[0] | ((unsigned)lo[1]<<16), (unsigned)lo[2] | ((unsigned)lo[3]<<16),
                (unsigned)lo[4] | ((unsigned)lo[5]<<16), (unsigned)lo[6] | ((unsigned)lo[7]<<16) };
    Af2[(blk*2 + 0)*64 + l] = H;
    Af2[(blk*2 + 1)*64 + l] = L;
}

// ---------------- prep: W -> bf16 B-fragment layout (16x16x32) ----------------
__global__ void prep_W(const float* __restrict__ W, const float* __restrict__ gamma,
                       unsigned int* __restrict__ Wf){
    int fidx = blockIdx.x;              // 0..95
    int ot = fidx & 7, c0 = (fidx >> 3) & 3, k = fidx >> 5;
    int l = threadIdx.x;                // 0..63
    int o = ot*16 + (l & 15);
    int cb = c0*32 + ((l >> 4) << 3);
    float scale = gamma[o] * rsqrtf(1.0f + BN_EPS) * (1.0f/3.0f);
    const float* wr = W + (k*128 + o)*128 + cb;
    unsigned int p0, p1, p2, p3;
    p0 = (unsigned int)bf16bits(wr[0]*scale) | ((unsigned int)bf16bits(wr[1]*scale) << 16);
    p1 = (unsigned int)bf16bits(wr[2]*scale) | ((unsigned int)bf16bits(wr[3]*scale) << 16);
    p2 = (unsigned int)bf16bits(wr[4]*scale) | ((unsigned int)bf16bits(wr[5]*scale) << 16);
    p3 = (unsigned int)bf16bits(wr[6]*scale) | ((unsigned int)bf16bits(wr[7]*scale) << 16);
    u32x4 v = {p0, p1, p2, p3};
    ((u32x4*)Wf)[fidx*64 + l] = v;
}

// ---------------- main fused kernel ----------------
// grid (128 tiles of 50 m, 64 b), 512 threads (8 waves). LDS 76800 B:
//   [0, 49152): XA bf16 [64 m][384 kc], XOR-swizzled; overlaid by outstage
//               fp32 [128 o][65 m] (33280 B) after P2.
//   [49152, 76800): x slab fp32 [128 c][54], staged once, used by P1 + P4.
__global__ __launch_bounds__(512) void gcn_main(
    const float* __restrict__ x, const u32x4* __restrict__ Af2,
    const unsigned int* __restrict__ Wf, const float* __restrict__ beta,
    float* __restrict__ out){
    extern __shared__ char smem[];
    float* slab = (float*)(smem + 49152);
    const int tile = blockIdx.x;           // 0..127
    const int b    = blockIdx.y;           // 0..63
    const int tid  = threadIdx.x;
    const int lane = tid & 63;
    const int wv   = tid >> 6;
    const int m0g  = tile * 50;
    const int t0   = tile * 2;             // 50 = 2*25, t-aligned

    // ================= P0: stage x slab fp32, coalesced float2 =================
    {
        const int xbase = (b*128)*6400 + t0*25;
        for (int j2 = tid; j2 < 3200; j2 += 512){
            int c = j2 / 25, tv2 = (j2 - c*25) * 2;
            float2 v = *(const float2*)(x + xbase + c*6400 + tv2);
            *(float2*)(slab + c*54 + tv2) = v;
        }
    }
    __syncthreads();

    // ================= P1: XA via MFMA 32x32x16 (x from slab) =================
    // wave task: (c32 = wv&3, tt = wv>>2). lane&31 = c-row for A, = w-col for D.
    {
        const int c32 = wv & 3, tt = wv >> 2;
        const int lw  = lane & 31, g5 = lane >> 5;
        const int c   = c32*32 + lw;
        const float* xr = slab + c*54 + tt*25;

        float a0f[8], a1f[8];
        #pragma unroll
        for (int i = 0; i < 8; ++i) a0f[i] = xr[g5*8 + i];        // v = g5*8+i (<16)
        if (g5 == 0){
            #pragma unroll
            for (int i = 0; i < 8; ++i) a1f[i] = xr[16 + i];      // v 16..23
        } else {
            a1f[0] = xr[24];                                      // v 24; 25..31 pad
            #pragma unroll
            for (int i = 1; i < 8; ++i) a1f[i] = 0.f;
        }
        u16x8 ua0, ua1;
        #pragma unroll
        for (int i = 0; i < 8; ++i){ ua0[i] = bf16bits(a0f[i]); ua1[i] = bf16bits(a1f[i]); }
        bf16x8 A0 = __builtin_bit_cast(bf16x8, ua0);
        bf16x8 A1 = __builtin_bit_cast(bf16x8, ua1);

        const int mrow  = tt*25 + lw;            // XA row (w<25 valid)
        const int mbyte = mrow * 768;
        const int swzb  = (mrow & 7) << 4;

        for (int k = 0; k < 3; ++k){
            u32x4 B0h = Af2[((k*2+0)*2 + 0)*64 + lane];
            u32x4 B0l = Af2[((k*2+0)*2 + 1)*64 + lane];
            u32x4 B1h = Af2[((k*2+1)*2 + 0)*64 + lane];
            u32x4 B1l = Af2[((k*2+1)*2 + 1)*64 + lane];
            f32x16 acc;
            #pragma unroll
            for (int e = 0; e < 16; ++e) acc[e] = 0.f;
            acc = __builtin_amdgcn_mfma_f32_32x32x16_bf16(A1, __builtin_bit_cast(bf16x8, B1l), acc, 0,0,0);
            acc = __builtin_amdgcn_mfma_f32_32x32x16_bf16(A0, __builtin_bit_cast(bf16x8, B0l), acc, 0,0,0);
            acc = __builtin_amdgcn_mfma_f32_32x32x16_bf16(A1, __builtin_bit_cast(bf16x8, B1h), acc, 0,0,0);
            acc = __builtin_amdgcn_mfma_f32_32x32x16_bf16(A0, __builtin_bit_cast(bf16x8, B0h), acc, 0,0,0);
            if (lw < 25){
                #pragma unroll
                for (int q = 0; q < 4; ++q){
                    int rowD = 8*q + 4*g5;                         // D rows rowD..rowD+3
                    int kc   = k*128 + c32*32 + rowD;
                    unsigned int d0 = (unsigned int)bf16bits(acc[4*q+0]) | ((unsigned int)bf16bits(acc[4*q+1]) << 16);
                    unsigned int d1 = (unsigned int)bf16bits(acc[4*q+2]) | ((unsigned int)bf16bits(acc[4*q+3]) << 16);
                    int byteoff = (mbyte + kc*2) ^ swzb;
                    uint2 vv = {d0, d1};
                    *(uint2*)(smem + byteoff) = vv;
                }
            }
        }
    }
    __syncthreads();

    // ================= P2: GEMM via MFMA 16x16x32 over kc=384 =================
    const int mh = wv >> 2;                 // 0..1 : m-half (32 rows)
    const int oq = wv & 3;                  // 0..3 : o-quarter (32 cols)
    const int r = lane & 15, g = lane >> 4;
    const int swz = (r & 7) << 4;
    f32x4 acc00 = {0.f,0.f,0.f,0.f}, acc01 = {0.f,0.f,0.f,0.f};
    f32x4 acc10 = {0.f,0.f,0.f,0.f}, acc11 = {0.f,0.f,0.f,0.f};
    const int abU0 = (mh*32 + r) * 768 + g*16;   // unswizzled byte base (+ks*64)
    const int abU1 = abU0 + 16*768;
    const u32x4* WfV = (const u32x4*)Wf;
    const int ot0 = oq*2, ot1 = ot0 + 1;
    u32x4 b0 = WfV[(ot0)*64 + lane];
    u32x4 b1 = WfV[(ot1)*64 + lane];
    #pragma unroll
    for (int ks = 0; ks < 12; ++ks){
        u32x4 nb0 = b0, nb1 = b1;
        if (ks < 11){
            nb0 = WfV[((ks+1)*8 + ot0)*64 + lane];
            nb1 = WfV[((ks+1)*8 + ot1)*64 + lane];
        }
        bf16x8 a0 = *(const bf16x8*)(smem + ((abU0 + ks*64) ^ swz));
        bf16x8 a1 = *(const bf16x8*)(smem + ((abU1 + ks*64) ^ swz));
        bf16x8 f0 = __builtin_bit_cast(bf16x8, b0);
        bf16x8 f1 = __builtin_bit_cast(bf16x8, b1);
        acc00 = __builtin_amdgcn_mfma_f32_16x16x32_bf16(a0, f0, acc00, 0, 0, 0);
        acc01 = __builtin_amdgcn_mfma_f32_16x16x32_bf16(a0, f1, acc01, 0, 0, 0);
        acc10 = __builtin_amdgcn_mfma_f32_16x16x32_bf16(a1, f0, acc10, 0, 0, 0);
        acc11 = __builtin_amdgcn_mfma_f32_16x16x32_bf16(a1, f1, acc11, 0, 0, 0);
        b0 = nb0; b1 = nb1;
    }
    __syncthreads();

    // ================= P3: acc -> outstage fp32 [o][65] (overlays XA) =========
    // D[m = g*4+e (+16)][o = r (+16)]; garbage rows m=50..63 land in stride-65 pad.
    {
        float* outst = (float*)smem;
        #pragma unroll
        for (int e = 0; e < 4; ++e){
            int o0 = oq*32 + r, o1 = o0 + 16;
            int mA = mh*32 + g*4 + e, mB = mA + 16;
            outst[o0*65 + mA] = acc00[e];
            outst[o1*65 + mA] = acc01[e];
            outst[o0*65 + mB] = acc10[e];
            outst[o1*65 + mB] = acc11[e];
        }
    }
    __syncthreads();

    // ================= P4: epilogue (+beta, hswish, +x from slab, hswish) =====
    {
        const float* outst = (const float*)smem;
        int o = tid >> 2, q = tid & 3;
        float bet = beta[o];
        int obase = (b*128 + o)*6400 + m0g;
        int nj = (q < 3) ? 8 : 1;              // q=3 covers only m=48,49
        for (int j2 = 0; j2 < nj; ++j2){
            int m = q*16 + 2*j2;
            float v0 = outst[o*65 + m];
            float v1 = outst[o*65 + m + 1];
            float x0 = slab[o*54 + m];
            float x1 = slab[o*54 + m + 1];
            float r0 = hswish(hswish(v0 + bet) + x0);
            float r1 = hswish(hswish(v1 + bet) + x1);
            float2 res = {r0, r1};
            *(float2*)(out + obase + m) = res;
        }
    }
}

extern "C" void kernel_launch(void* const* d_in, const int* in_sizes, int n_in,
                              void* d_out, int out_size, void* d_ws, size_t ws_size,
                              hipStream_t stream) {
    const float* x      = (const float*)d_in[0];
    const float* Afix   = (const float*)d_in[1];
    const float* Alrn   = (const float*)d_in[2];
    const float* Wg     = (const float*)d_in[3];
    const float* gamma  = (const float*)d_in[4];
    const float* beta   = (const float*)d_in[5];
    float* out = (float*)d_out;

    float*        Atv = (float*)d_ws;                                // 9600 B
    unsigned int* Wf  = (unsigned int*)((char*)d_ws + 16384);        // 98304 B
    u32x4*        Af2 = (u32x4*)((char*)d_ws + 118784);              // 12288 B

    (void)hipFuncSetAttribute((const void*)gcn_main,
                              hipFuncAttributeMaxDynamicSharedMemorySize, 76800);

    prep_A<<<dim3(3), 256, 0, stream>>>(Afix, Alrn, Atv);
    prep_Afrag<<<dim3(6), 64, 0, stream>>>(Atv, Af2);
    prep_W<<<dim3(96), 64, 0, stream>>>(Wg, gamma, Wf);
    gcn_main<<<dim3(128, 64), 512, 76800, stream>>>(x, Af2, Wf, beta, out);
}